// Round 13
// baseline (4915.427 us; speedup 1.0000x reference)
//
#include <hip/hip_runtime.h>
#include <hip/hip_bf16.h>

#define DEV __device__ __forceinline__

constexpr int B_ = 256;   // batch
constexpr int T_ = 512;   // time
constexpr int H_ = 128;   // GRU units
constexpr int K_ = 256;   // input dim per layer (D = 2H = 256 for all layers)
constexpr int G_ = 384;   // 3H
constexpr int M_ = B_ * T_;

using bf16 = __hip_bfloat16;
typedef short bf16x8 __attribute__((ext_vector_type(8)));
typedef float f32x4 __attribute__((ext_vector_type(4)));
typedef float f32x2 __attribute__((ext_vector_type(2)));

DEV float tof(float x) { return x; }
DEV float tof(bf16 x) { return __bfloat162float(x); }
DEV void stor(float* p, float v) { *p = v; }
DEV void stor(bf16* p, float v) { *p = __float2bfloat16(v); }

// float -> bf16 bits, round-to-nearest-even
DEV unsigned short f2bs(float f) {
  union { float f; unsigned u; } v;
  v.f = f;
  unsigned r = (v.u + 0x7FFFu + ((v.u >> 16) & 1u)) >> 16;
  return (unsigned short)r;
}
DEV float bs2f(unsigned short s) {
  union { unsigned u; float f; } v;
  v.u = ((unsigned)s) << 16;
  return v.f;
}

// v7: fast-rcp gate math (measured −25us/launch vs IEEE div).
DEV float fsigmoid(float x) {
  return __builtin_amdgcn_rcpf(1.f + __expf(-x));
}
DEV float ftanh(float x) {
  x = fminf(20.f, fmaxf(-20.f, x));
  float e = __expf(-2.f * x);
  return (1.f - e) * __builtin_amdgcn_rcpf(1.f + e);
}

// Barrier draining only LDS traffic (lgkmcnt), not global loads/stores.
DEV void barrier_lds() {
  asm volatile("s_waitcnt lgkmcnt(0)\n\ts_barrier" ::: "memory");
}

// Pin a float4 into VGPRs (opaque to the optimizer).
DEV void pin4(float4& v) {
  asm volatile("" : "+v"(v.x), "+v"(v.y), "+v"(v.z), "+v"(v.w));
}

DEV f32x4 mfma16(bf16x8 a, bf16x8 b, f32x4 c) {
  return __builtin_amdgcn_mfma_f32_16x16x32_bf16(a, b, c, 0, 0, 0);
}

// Async global->LDS, 16B per lane: LDS dest = wave-uniform base + lane*16,
// global source is per-lane (m104/m108 semantics).
DEV void gload16(const ushort* g, ushort* l) {
  __builtin_amdgcn_global_load_lds(
      (const __attribute__((address_space(1))) void*)g,
      (__attribute__((address_space(3))) void*)l, 16, 0, 0);
}

// Single-stage DPP exchanges within 8-lane groups (bound_ctrl, full masks).
DEV float dppx1(float x) {  // lane ^ 1 (quad_perm [1,0,3,2])
  return __int_as_float(
      __builtin_amdgcn_update_dpp(0, __float_as_int(x), 0xB1, 0xF, 0xF, true));
}
DEV float dppx2(float x) {  // lane ^ 2 (quad_perm [2,3,0,1])
  return __int_as_float(
      __builtin_amdgcn_update_dpp(0, __float_as_int(x), 0x4E, 0xF, 0xF, true));
}
DEV float dppx7(float x) {  // lane ^ 7 (row_half_mirror)
  return __int_as_float(
      __builtin_amdgcn_update_dpp(0, __float_as_int(x), 0x141, 0xF, 0xF, true));
}

// ---------------------------------------------------------------------------
// convX: split fp32 x[M,256] into bf16 hi/lo arrays (layer-0 GEMM input).
// ---------------------------------------------------------------------------
__global__ __launch_bounds__(256) void convX_kernel(
    const float* __restrict__ x, ushort* __restrict__ hiA,
    ushort* __restrict__ loA) {
  const int n4 = M_ * K_ / 4;
  for (int idx = blockIdx.x * blockDim.x + threadIdx.x; idx < n4;
       idx += gridDim.x * blockDim.x) {
    float4 v = ((const float4*)x)[idx];
    ushort4 h, l;
    h.x = f2bs(v.x); l.x = f2bs(v.x - bs2f(h.x));
    h.y = f2bs(v.y); l.y = f2bs(v.y - bs2f(h.y));
    h.z = f2bs(v.z); l.z = f2bs(v.z - bs2f(h.z));
    h.w = f2bs(v.w); l.w = f2bs(v.w - bs2f(h.w));
    ((ushort4*)hiA)[idx] = h;
    ((ushort4*)loA)[idx] = l;
  }
}

// ---------------------------------------------------------------------------
// convW: W[dir][256][384] fp32 -> W^T hi/lo bf16 [768 ncol][256 k].
// ---------------------------------------------------------------------------
__global__ __launch_bounds__(256) void convW_kernel(
    const float* __restrict__ W, ushort* __restrict__ WhiT,
    ushort* __restrict__ WloT) {
  const int ncol = blockIdx.x;           // 0..767
  const int dir = ncol / G_, j = ncol % G_;
  const int k = threadIdx.x;             // 0..255
  const float f = W[((size_t)dir * K_ + k) * G_ + j];
  const unsigned short hi = f2bs(f);
  WhiT[(size_t)ncol * K_ + k] = hi;
  WloT[(size_t)ncol * K_ + k] = f2bs(f - bs2f(hi));
}

// ---------------------------------------------------------------------------
// gemm3: C[M,768] = A[M,256] @ W^T' + bias, bf16 hi/lo 3-term split MFMA.
// v9 staging: global_load_lds width=16, linear LDS dest, inverse-swizzled
// global source + XOR-swizzled read (rule #21).
// ---------------------------------------------------------------------------
template <typename XT>
__global__ __launch_bounds__(256, 2) void gemm3_kernel(
    const ushort* __restrict__ Ahi, const ushort* __restrict__ Alo,
    const ushort* __restrict__ WhiT, const ushort* __restrict__ WloT,
    const float* __restrict__ bbias, XT* __restrict__ xp) {
  const int m0 = blockIdx.x * 128;
  const int n0 = blockIdx.y * 128;
  const int tid = threadIdx.x;
  const int w = tid >> 6, lane = tid & 63;
  const int wm = w >> 1, wn = w & 1;
  const int col = lane & 15, quad = lane >> 4;

  __shared__ __align__(16) ushort AH[128 * 64];
  __shared__ __align__(16) ushort AL[128 * 64];
  __shared__ __align__(16) ushort BH[128 * 64];
  __shared__ __align__(16) ushort BL[128 * 64];

  f32x4 acc[4][4];
#pragma unroll
  for (int i = 0; i < 4; ++i)
#pragma unroll
    for (int n = 0; n < 4; ++n) acc[i][n] = (f32x4){0.f, 0.f, 0.f, 0.f};

  const ushort* gsrc = (w == 0) ? Ahi : (w == 1) ? Alo : (w == 2) ? WhiT : WloT;
  ushort* lds = (w == 0) ? AH : (w == 1) ? AL : (w == 2) ? BH : BL;
  const int rbase = (w < 2) ? m0 : n0;

  const int srow = lane >> 3;          // row offset within each q-group of 8
  const int sl = lane & 7;             // linear LDS 16B slot within row

  for (int kb = 0; kb < K_; kb += 64) {
#pragma unroll
    for (int q = 0; q < 16; ++q) {
      const int r = q * 8 + srow;
      const int sc = sl ^ (r & 7);     // inverse-swizzled source chunk
      gload16(gsrc + (size_t)(rbase + r) * K_ + kb + sc * 8, lds + q * 512);
    }
    __syncthreads();
#pragma unroll
    for (int z = 0; z < 2; ++z) {
      const int qk = z * 4 + quad;
      bf16x8 ah[4], al[4], bh[4], bl[4];
#pragma unroll
      for (int i = 0; i < 4; ++i) {
        const int row = wm * 64 + i * 16 + col;
        const int off = row * 64 + ((qk ^ (row & 7)) << 3);
        ah[i] = *(const bf16x8*)&AH[off];
        al[i] = *(const bf16x8*)&AL[off];
      }
#pragma unroll
      for (int n = 0; n < 4; ++n) {
        const int row = wn * 64 + n * 16 + col;
        const int off = row * 64 + ((qk ^ (row & 7)) << 3);
        bh[n] = *(const bf16x8*)&BH[off];
        bl[n] = *(const bf16x8*)&BL[off];
      }
#pragma unroll
      for (int i = 0; i < 4; ++i)
#pragma unroll
        for (int n = 0; n < 4; ++n) {
          acc[i][n] = mfma16(ah[i], bh[n], acc[i][n]);
          acc[i][n] = mfma16(al[i], bh[n], acc[i][n]);
          acc[i][n] = mfma16(ah[i], bl[n], acc[i][n]);
        }
    }
    __syncthreads();
  }

  const int dir = (n0 >= G_) ? 1 : 0;
#pragma unroll
  for (int n = 0; n < 4; ++n) {
    const int ncol = n0 + wn * 64 + n * 16 + col;
    const int g = ncol - dir * G_;
    const float bv = bbias[dir * 2 * G_ + g];
#pragma unroll
    for (int i = 0; i < 4; ++i) {
      const int mb = m0 + wm * 64 + i * 16 + quad * 4;
#pragma unroll
      for (int r = 0; r < 4; ++r) {
        const int m = mb + r;
        const int bb = m >> 9;          // T_ = 512
        const int t = m & (T_ - 1);
        stor(xp + ((size_t)(dir * T_ + t) * B_ + bb) * G_ + g,
             acc[i][n][r] + bv);
      }
    }
  }
}

DEV float4 ldU4(const float* U, int col, int k0) {
  float4 v;
  v.x = U[(size_t)(k0 + 0) * G_ + col];
  v.y = U[(size_t)(k0 + 1) * G_ + col];
  v.z = U[(size_t)(k0 + 2) * G_ + col];
  v.w = U[(size_t)(k0 + 3) * G_ + col];
  return v;
}

// ---------------------------------------------------------------------------
// Recurrence, v11 = v10 structure with waves_per_eu(6,6) — BOTH min AND max.
// v10 post-mortem: waves_per_eu(6) (min-only) let RA target 8 waves/EU
// (64-reg budget) and spill all 64 pinned U regs (VGPR_Count=40, 1440us) —
// the SAME failure as v6, and the same fix as v4->v5 ((2,2) pins max).
// (6,6) pins the budget at 512/6 = 85 regs >= the ~60 this structure needs
// (v8 measured 68 with 2x the accumulators). The structure itself is
// VALIDATED: v10 passed (permutation g correct) and reached 71% occupancy
// (2 blocks/CU co-residency works) — it was only running U from scratch.
//
// Thread = 4 cols x k-eighth x 1 row. 1-row reduce-scatter tree:
//   g(kc) = (kc&1?2:0) ^ (kc&4?3:0)
//   stage1 xor1 (payload delta 2), stage2 xor7 (delta 1), stage3 xor2
//   (delta 0; lanes l and l^2 end duplicated, kc&2==0 writes).
// ---------------------------------------------------------------------------
template <typename XT, bool LAST>
__global__ __attribute__((amdgpu_flat_work_group_size(768, 768),
                          amdgpu_waves_per_eu(6, 6))) void rec_kernel(
    const XT* __restrict__ xp, const float* __restrict__ Ubase,
    const float* __restrict__ bbase, ushort* __restrict__ seqH,
    ushort* __restrict__ seqL, float* __restrict__ fin) {
  const int dir = blockIdx.y;
  const int b = blockIdx.x;
  const float* U = Ubase + dir * (H_ * G_);
  const float* bh = bbase + dir * (2 * G_) + G_;
  const int tid = threadIdx.x;
  const int kc = tid & 7;        // position within 8-lane DPP group
  const int cg = tid >> 3;       // column group 0..95
  const int kc4 = kc * 4;

  // Reduce-scatter permutation (see header comment).
  const int g = ((kc & 1) ? 2 : 0) ^ ((kc & 4) ? 3 : 0);

  __shared__ __align__(16) float hbuf[H_];
  __shared__ float rec_s[G_];

  // U fragments: u{m}{i} covers col cg*4 + (m ^ g), k in [i*32+kc*4, +4)
#define LDU(m, i) ldU4(U, cg * 4 + ((m) ^ g), (i) * 32 + kc4)
  float4 u00 = LDU(0, 0), u01 = LDU(0, 1), u02 = LDU(0, 2), u03 = LDU(0, 3);
  float4 u10 = LDU(1, 0), u11 = LDU(1, 1), u12 = LDU(1, 2), u13 = LDU(1, 3);
  float4 u20 = LDU(2, 0), u21 = LDU(2, 1), u22 = LDU(2, 2), u23 = LDU(2, 3);
  float4 u30 = LDU(3, 0), u31 = LDU(3, 1), u32 = LDU(3, 2), u33 = LDU(3, 3);
#undef LDU
  pin4(u00); pin4(u01); pin4(u02); pin4(u03);
  pin4(u10); pin4(u11); pin4(u12); pin4(u13);
  pin4(u20); pin4(u21); pin4(u22); pin4(u23);
  pin4(u30); pin4(u31); pin4(u32); pin4(u33);

  // This lane's final output after the tree: col cg*4 + g.
  const float bmine = bh[cg * 4 + g];

  const int gu = tid;               // gate-phase unit (tid < 128)
  const bool gateT = tid < H_;

  if (gateT) hbuf[gu] = 0.f;

  const XT* xbase = xp + (size_t)(dir * T_) * B_ * G_;

  XT xzc{}, xrc{}, xhc{};
  {
    const int t0 = dir ? (T_ - 1) : 0;
    if (gateT) {
      const XT* xr_ = xbase + ((size_t)t0 * B_ + b) * G_ + gu;
      xzc = xr_[0];
      xrc = xr_[H_];
      xhc = xr_[2 * H_];
    }
  }
  float hprev = 0.f;   // gate thread's own h, carried in-register
  barrier_lds();

  for (int it = 0; it < T_; ++it) {
    const int t = dir ? (T_ - 1 - it) : it;

    // --- prefetch xp for step it+1 (hidden under the dot phase) ---
    XT xzn = xzc, xrn = xrc, xhn = xhc;
    if (gateT && (it + 1 < T_)) {
      const int tn = dir ? (t - 1) : (t + 1);
      const XT* xr_ = xbase + ((size_t)tn * B_ + b) * G_ + gu;
      xzn = xr_[0];
      xrn = xr_[H_];
      xhn = xr_[2 * H_];
    }

    // --- dot phase: 4 cols x 16 k, 4 broadcast b128 reads, 32 pk_fma ---
    f32x2 a0 = {0.f, 0.f}, a1 = {0.f, 0.f}, a2 = {0.f, 0.f}, a3 = {0.f, 0.f};
#define FMA2(acc, h4, u4)                                              \
  {                                                                    \
    const f32x2* hp_ = (const f32x2*)&(h4);                            \
    const f32x2* up_ = (const f32x2*)&(u4);                            \
    acc = __builtin_elementwise_fma(hp_[0], up_[0], acc);              \
    acc = __builtin_elementwise_fma(hp_[1], up_[1], acc);              \
  }
#define DOT_I(i, uA, uB, uC, uD)                                       \
  {                                                                    \
    float4 h0 = *(const float4*)&hbuf[(i) * 32 + kc4];                 \
    FMA2(a0, h0, uA) FMA2(a1, h0, uB) FMA2(a2, h0, uC) FMA2(a3, h0, uD)\
  }
    DOT_I(0, u00, u10, u20, u30)
    DOT_I(1, u01, u11, u21, u31)
    DOT_I(2, u02, u12, u22, u32)
    DOT_I(3, u03, u13, u23, u33)
#undef DOT_I
#undef FMA2

    // Horizontal adds: s[m] = partial sum for col cg*4 + (m ^ g).
    const float s0 = a0.x + a0.y;
    const float s1 = a1.x + a1.y;
    const float s2 = a2.x + a2.y;
    const float s3 = a3.x + a3.y;

    // Reduce-scatter tree: stage1 xor1 (d2), stage2 xor7 (d1), stage3 xor2.
    const float r0 = s0 + dppx1(s2);
    const float r1 = s1 + dppx1(s3);
    const float t0v = r0 + dppx7(r1);
    const float v = t0v + dppx2(t0v);

    if ((kc & 2) == 0) rec_s[cg * 4 + g] = v + bmine;
    barrier_lds();

    // --- gate phase (first 128 threads; co-resident block overlaps) ---
    if (gateT) {
      const float xz = tof(xzc);
      const float xr = tof(xrc);
      const float xh = tof(xhc);
      const float rz = rec_s[gu];
      const float rr = rec_s[H_ + gu];
      const float rh = rec_s[2 * H_ + gu];
      const float z = fsigmoid(xz + rz);
      const float r = fsigmoid(xr + rr);
      const float hh = ftanh(xh + r * rh);
      const float hn = z * hprev + (1.f - z) * hh;
      hprev = hn;
      hbuf[gu] = hn;
      if constexpr (!LAST) {
        const size_t sidx = ((size_t)b * T_ + t) * (2 * H_) + dir * H_ + gu;
        const unsigned short hi = f2bs(hn);
        seqH[sidx] = hi;
        seqL[sidx] = f2bs(hn - bs2f(hi));
      }
      xzc = xzn;
      xrc = xrn;
      xhc = xhn;
    }
    barrier_lds();
  }

  if constexpr (LAST) {
    if (gateT) fin[(size_t)b * (2 * H_) + dir * H_ + gu] = hprev;
  }
}

// ---------------------------------------------------------------------------
// Dense head: out[b] = sigmoid(fin[b][:] . Wd + bd)
// ---------------------------------------------------------------------------
__global__ void dense_kernel(const float* __restrict__ fin,
                             const float* __restrict__ Wd,
                             const float* __restrict__ bd,
                             float* __restrict__ out) {
  __shared__ float w[2 * H_];
  const int tid = threadIdx.x;
  w[tid] = Wd[tid];
  __syncthreads();
  float s = bd[0];
  const float* row = fin + tid * (2 * H_);
#pragma unroll 8
  for (int jj = 0; jj < 2 * H_; ++jj) s = fmaf(row[jj], w[jj], s);
  out[tid] = 1.f / (1.f + __expf(-s));
}

// ---------------------------------------------------------------------------
template <typename XT>
static void run_model(const float* x, const float* Ws, const float* Us,
                      const float* bs, const float* Wd, const float* bd,
                      float* out, char* ws, hipStream_t stream) {
  const size_t xpB = (size_t)2 * T_ * B_ * G_ * sizeof(XT);
  const size_t seqB = (size_t)B_ * T_ * 2 * H_ * 2;  // bf16 bits
  XT* xp = (XT*)ws;
  ushort* sHA = (ushort*)(ws + xpB);
  ushort* sLA = (ushort*)(ws + xpB + seqB);
  ushort* sHB = (ushort*)(ws + xpB + 2 * seqB);
  ushort* sLB = (ushort*)(ws + xpB + 3 * seqB);
  ushort* WhiT = (ushort*)(ws + xpB + 4 * seqB);
  ushort* WloT = WhiT + (size_t)768 * K_;
  float* fin = (float*)(ws + xpB + 4 * seqB + (size_t)2 * 768 * K_ * 2);

  convX_kernel<<<4096, 256, 0, stream>>>(x, sHB, sLB);

  const ushort* AHs[3] = {sHB, sHA, sHB};
  const ushort* ALs[3] = {sLB, sLA, sLB};
  ushort* oH[3] = {sHA, sHB, nullptr};
  ushort* oL[3] = {sLA, sLB, nullptr};

  for (int l = 0; l < 3; ++l) {
    const float* Wl = Ws + (size_t)l * 2 * K_ * G_;
    const float* bl = bs + (size_t)l * 4 * G_;
    const float* Ul = Us + (size_t)l * 2 * H_ * G_;
    convW_kernel<<<768, 256, 0, stream>>>(Wl, WhiT, WloT);
    gemm3_kernel<XT><<<dim3(M_ / 128, 6), 256, 0, stream>>>(
        AHs[l], ALs[l], WhiT, WloT, bl, xp);
    if (l < 2)
      rec_kernel<XT, false><<<dim3(B_, 2), 768, 0, stream>>>(
          xp, Ul, bl, oH[l], oL[l], nullptr);
    else
      rec_kernel<XT, true><<<dim3(B_, 2), 768, 0, stream>>>(
          xp, Ul, bl, nullptr, nullptr, fin);
  }
  dense_kernel<<<1, B_, 0, stream>>>(fin, Wd, bd, out);
}

extern "C" void kernel_launch(void* const* d_in, const int* in_sizes, int n_in,
                              void* d_out, int out_size, void* d_ws,
                              size_t ws_size, hipStream_t stream) {
  const float* x = (const float*)d_in[0];
  const float* Ws = (const float*)d_in[1];
  const float* Us = (const float*)d_in[2];
  const float* bs = (const float*)d_in[3];
  const float* Wd = (const float*)d_in[4];
  const float* bd = (const float*)d_in[5];
  float* out = (float*)d_out;
  char* ws = (char*)d_ws;

  const size_t seqB = (size_t)B_ * T_ * 2 * H_ * 2;
  const size_t wtB = (size_t)2 * 768 * K_ * 2;
  const size_t finB = (size_t)B_ * 2 * H_ * 4;
  const size_t xp32 = (size_t)2 * T_ * B_ * G_ * 4;
  const size_t tierA = xp32 + 4 * seqB + wtB + finB;      // ~641 MiB, fp32 xp
  if (ws_size >= tierA)
    run_model<float>(x, Ws, Us, bs, Wd, bd, out, ws, stream);
  else
    run_model<bf16>(x, Ws, Us, bs, Wd, bd, out, ws, stream);
}

// Round 14
// 2035.505 us; speedup vs baseline: 2.4148x; 2.4148x over previous
//
#include <hip/hip_runtime.h>
#include <hip/hip_bf16.h>

#define DEV __device__ __forceinline__

constexpr int B_ = 256;   // batch
constexpr int T_ = 512;   // time
constexpr int H_ = 128;   // GRU units
constexpr int K_ = 256;   // input dim per layer (D = 2H = 256 for all layers)
constexpr int G_ = 384;   // 3H
constexpr int M_ = B_ * T_;
constexpr int LDSROW = 72;  // ushorts per LDS tile row (64 data + 8 pad)

using bf16 = __hip_bfloat16;
typedef short bf16x8 __attribute__((ext_vector_type(8)));
typedef float f32x4 __attribute__((ext_vector_type(4)));
typedef _Float16 half2 __attribute__((ext_vector_type(2)));

DEV float tof(float x) { return x; }
DEV float tof(bf16 x) { return __bfloat162float(x); }
DEV void stor(float* p, float v) { *p = v; }
DEV void stor(bf16* p, float v) { *p = __float2bfloat16(v); }

// float -> bf16 bits, round-to-nearest-even
DEV unsigned short f2bs(float f) {
  union { float f; unsigned u; } v;
  v.f = f;
  unsigned r = (v.u + 0x7FFFu + ((v.u >> 16) & 1u)) >> 16;
  return (unsigned short)r;
}
DEV float bs2f(unsigned short s) {
  union { unsigned u; float f; } v;
  v.u = ((unsigned)s) << 16;
  return v.f;
}

// v7: fast-rcp gate math (measured −25us/launch vs IEEE div).
DEV float fsigmoid(float x) {
  return __builtin_amdgcn_rcpf(1.f + __expf(-x));
}
DEV float ftanh(float x) {
  x = fminf(20.f, fmaxf(-20.f, x));
  float e = __expf(-2.f * x);
  return (1.f - e) * __builtin_amdgcn_rcpf(1.f + e);
}

// Barrier draining only LDS traffic (lgkmcnt), not global loads/stores.
DEV void barrier_lds() {
  asm volatile("s_waitcnt lgkmcnt(0)\n\ts_barrier" ::: "memory");
}

// Pin a 32-bit half2 into a VGPR (opaque to the optimizer).
DEV void pinh(half2& v) { asm volatile("" : "+v"(v)); }

DEV f32x4 mfma16(bf16x8 a, bf16x8 b, f32x4 c) {
  return __builtin_amdgcn_mfma_f32_16x16x32_bf16(a, b, c, 0, 0, 0);
}

// Single-stage DPP exchanges within 8-lane groups (bound_ctrl, full masks).
DEV float dppx1(float x) {  // lane ^ 1 (quad_perm [1,0,3,2])
  return __int_as_float(
      __builtin_amdgcn_update_dpp(0, __float_as_int(x), 0xB1, 0xF, 0xF, true));
}
DEV float dppx2(float x) {  // lane ^ 2 (quad_perm [2,3,0,1])
  return __int_as_float(
      __builtin_amdgcn_update_dpp(0, __float_as_int(x), 0x4E, 0xF, 0xF, true));
}
DEV float dppx7(float x) {  // lane ^ 7 (row_half_mirror)
  return __int_as_float(
      __builtin_amdgcn_update_dpp(0, __float_as_int(x), 0x141, 0xF, 0xF, true));
}

// ---------------------------------------------------------------------------
// convX: split fp32 x[M,256] into bf16 hi/lo arrays (layer-0 GEMM input).
// ---------------------------------------------------------------------------
__global__ __launch_bounds__(256) void convX_kernel(
    const float* __restrict__ x, ushort* __restrict__ hiA,
    ushort* __restrict__ loA) {
  const int n4 = M_ * K_ / 4;
  for (int idx = blockIdx.x * blockDim.x + threadIdx.x; idx < n4;
       idx += gridDim.x * blockDim.x) {
    float4 v = ((const float4*)x)[idx];
    ushort4 h, l;
    h.x = f2bs(v.x); l.x = f2bs(v.x - bs2f(h.x));
    h.y = f2bs(v.y); l.y = f2bs(v.y - bs2f(h.y));
    h.z = f2bs(v.z); l.z = f2bs(v.z - bs2f(h.z));
    h.w = f2bs(v.w); l.w = f2bs(v.w - bs2f(h.w));
    ((ushort4*)hiA)[idx] = h;
    ((ushort4*)loA)[idx] = l;
  }
}

// ---------------------------------------------------------------------------
// convW: W[dir][256][384] fp32 -> W^T hi/lo bf16 [768 ncol][256 k].
// ---------------------------------------------------------------------------
__global__ __launch_bounds__(256) void convW_kernel(
    const float* __restrict__ W, ushort* __restrict__ WhiT,
    ushort* __restrict__ WloT) {
  const int ncol = blockIdx.x;           // 0..767
  const int dir = ncol / G_, j = ncol % G_;
  const int k = threadIdx.x;             // 0..255
  const float f = W[((size_t)dir * K_ + k) * G_ + j];
  const unsigned short hi = f2bs(f);
  WhiT[(size_t)ncol * K_ + k] = hi;
  WloT[(size_t)ncol * K_ + k] = f2bs(f - bs2f(hi));
}

// ---------------------------------------------------------------------------
// gemm3: C[M,768] = A[M,256] @ W^T' + bias, bf16 hi/lo 3-term split MFMA.
// (round-10 reg-staging version — measured-best total configuration)
// ---------------------------------------------------------------------------
template <typename XT>
__global__ __launch_bounds__(256, 2) void gemm3_kernel(
    const ushort* __restrict__ Ahi, const ushort* __restrict__ Alo,
    const ushort* __restrict__ WhiT, const ushort* __restrict__ WloT,
    const float* __restrict__ bbias, XT* __restrict__ xp) {
  const int m0 = blockIdx.x * 128;
  const int n0 = blockIdx.y * 128;
  const int tid = threadIdx.x;
  const int w = tid >> 6, lane = tid & 63;
  const int wm = w >> 1, wn = w & 1;
  const int col = lane & 15, quad = lane >> 4;

  __shared__ __align__(16) ushort AH[128 * LDSROW];
  __shared__ __align__(16) ushort AL[128 * LDSROW];
  __shared__ __align__(16) ushort BH[128 * LDSROW];
  __shared__ __align__(16) ushort BL[128 * LDSROW];

  f32x4 acc[4][4];
#pragma unroll
  for (int i = 0; i < 4; ++i)
#pragma unroll
    for (int n = 0; n < 4; ++n) acc[i][n] = (f32x4){0.f, 0.f, 0.f, 0.f};

  const ushort* gsrc = (w == 0) ? Ahi : (w == 1) ? Alo : (w == 2) ? WhiT : WloT;
  ushort* lds = (w == 0) ? AH : (w == 1) ? AL : (w == 2) ? BH : BL;
  const int rbase = (w < 2) ? m0 : n0;

  for (int kb = 0; kb < K_; kb += 64) {
#pragma unroll
    for (int q = 0; q < 16; ++q) {
      const int slot = q * 64 + lane;
      const int r = slot >> 3, s = slot & 7;
      bf16x8 v = *(const bf16x8*)(gsrc + (size_t)(rbase + r) * K_ + kb + s * 8);
      *(bf16x8*)&lds[r * LDSROW + s * 8] = v;
    }
    __syncthreads();
#pragma unroll
    for (int z = 0; z < 2; ++z) {
      const int cc8 = (z * 4 + quad) * 8;
      bf16x8 ah[4], al[4], bh[4], bl[4];
#pragma unroll
      for (int i = 0; i < 4; ++i) {
        const int row = wm * 64 + i * 16 + col;
        ah[i] = *(const bf16x8*)&AH[row * LDSROW + cc8];
        al[i] = *(const bf16x8*)&AL[row * LDSROW + cc8];
      }
#pragma unroll
      for (int n = 0; n < 4; ++n) {
        const int row = wn * 64 + n * 16 + col;
        bh[n] = *(const bf16x8*)&BH[row * LDSROW + cc8];
        bl[n] = *(const bf16x8*)&BL[row * LDSROW + cc8];
      }
#pragma unroll
      for (int i = 0; i < 4; ++i)
#pragma unroll
        for (int n = 0; n < 4; ++n) {
          acc[i][n] = mfma16(ah[i], bh[n], acc[i][n]);
          acc[i][n] = mfma16(al[i], bh[n], acc[i][n]);
          acc[i][n] = mfma16(ah[i], bl[n], acc[i][n]);
        }
    }
    __syncthreads();
  }

  const int dir = (n0 >= G_) ? 1 : 0;
#pragma unroll
  for (int n = 0; n < 4; ++n) {
    const int ncol = n0 + wn * 64 + n * 16 + col;
    const int g = ncol - dir * G_;
    const float bv = bbias[dir * 2 * G_ + g];
#pragma unroll
    for (int i = 0; i < 4; ++i) {
      const int mb = m0 + wm * 64 + i * 16 + quad * 4;
#pragma unroll
      for (int r = 0; r < 4; ++r) {
        const int m = mb + r;
        const int bb = m >> 9;          // T_ = 512
        const int t = m & (T_ - 1);
        stor(xp + ((size_t)(dir * T_ + t) * B_ + bb) * G_ + g,
             acc[i][n][r] + bv);
      }
    }
  }
}

// ---------------------------------------------------------------------------
// Recurrence, v12: f16-operand dot (v_dot2_f32_f16, fp32 accumulate).
//
// v11 post-mortem: gfx950 occupancy is TIERED (m69: waves/CU halves at
// vgpr={64,128,256}); min-waves>=6 forces the 32-wave tier (<=64 regs) and
// the allocator spills the 64 fp32 U regs to 40. Fix the PRESSURE, not the
// attribute: U and h as f16 with fdot2 (f16 mul, FP32 accumulate):
//  - U: 64 values -> 32 half2 regs; total live ~58 <= 64-reg tier
//  - h in LDS as _Float16: 2 ds_read_b128/thread/step (half the LDS bytes)
//  - 32 fdot2 = same MAC rate as 32 pk_fma, no horizontal adds
//  - NO waves_per_eu attribute (it caused every spill failure: v6/v10/v11)
// Grid (256,2) = 512 blocks, 1 seq/block, 768 thr -> 2 blocks/CU in the
// 32-wave tier; block A's gate/barrier idle covered by block B's dot.
// Accuracy: f16 operands (11-bit mantissa) + fp32 accum -> pre-gate error
// ~2e-4/step, gate-squashed; absmax has been invariant at 0.0039 across
// fp32/bf16 rec variants -> slack expected.
// Thread = 4 cols x 16 contiguous k; v10's HW-validated reduce-scatter tree:
//   g(kc) = (kc&1?2:0) ^ (kc&4?3:0); stages xor1, xor7, xor2;
//   lanes l and l^2 end duplicated, kc&2==0 writes.
// ---------------------------------------------------------------------------
template <typename XT, bool LAST>
__global__ __attribute__((amdgpu_flat_work_group_size(768, 768))) void
rec_kernel(const XT* __restrict__ xp, const float* __restrict__ Ubase,
           const float* __restrict__ bbase, ushort* __restrict__ seqH,
           ushort* __restrict__ seqL, float* __restrict__ fin) {
  const int dir = blockIdx.y;
  const int b = blockIdx.x;
  const float* U = Ubase + dir * (H_ * G_);
  const float* bh = bbase + dir * (2 * G_) + G_;
  const int tid = threadIdx.x;
  const int kc = tid & 7;        // position within 8-lane DPP group
  const int cg = tid >> 3;       // column group 0..95

  // Reduce-scatter permutation (v10, HW-validated).
  const int g = ((kc & 1) ? 2 : 0) ^ ((kc & 4) ? 3 : 0);

  __shared__ __align__(16) _Float16 hbuf[H_];   // 256 B
  __shared__ float rec_s[G_];

  // U fragments: u[m][j] = f16 pair {U[k0], U[k0+1]} for col cg*4 + (m^g),
  // k0 = kc*16 + 2j. 32 half2 = 32 VGPRs.
  half2 u[4][8];
#pragma unroll
  for (int m = 0; m < 4; ++m) {
    const int colu = cg * 4 + (m ^ g);
#pragma unroll
    for (int j = 0; j < 8; ++j) {
      const int k0 = kc * 16 + 2 * j;
      u[m][j] = (half2){(_Float16)U[(size_t)k0 * G_ + colu],
                        (_Float16)U[(size_t)(k0 + 1) * G_ + colu]};
      pinh(u[m][j]);
    }
  }

  // This lane's final output after the tree: col cg*4 + g.
  const float bmine = bh[cg * 4 + g];

  const int gu = tid;               // gate-phase unit (tid < 128)
  const bool gateT = tid < H_;

  if (gateT) hbuf[gu] = (_Float16)0.f;

  const XT* xbase = xp + (size_t)(dir * T_) * B_ * G_;

  XT xzc{}, xrc{}, xhc{};
  {
    const int t0 = dir ? (T_ - 1) : 0;
    if (gateT) {
      const XT* xr_ = xbase + ((size_t)t0 * B_ + b) * G_ + gu;
      xzc = xr_[0];
      xrc = xr_[H_];
      xhc = xr_[2 * H_];
    }
  }
  float hprev = 0.f;   // gate thread's own h, carried in-register
  barrier_lds();

  for (int it = 0; it < T_; ++it) {
    const int t = dir ? (T_ - 1 - it) : it;

    // --- prefetch xp for step it+1 (hidden under the dot phase) ---
    XT xzn = xzc, xrn = xrc, xhn = xhc;
    if (gateT && (it + 1 < T_)) {
      const int tn = dir ? (t - 1) : (t + 1);
      const XT* xr_ = xbase + ((size_t)tn * B_ + b) * G_ + gu;
      xzn = xr_[0];
      xrn = xr_[H_];
      xhn = xr_[2 * H_];
    }

    // --- dot phase: 2 broadcast b128 reads of f16 h, 32 fdot2 ---
    float4 hv0 = *(const float4*)((const char*)hbuf + kc * 32);
    float4 hv1 = *(const float4*)((const char*)hbuf + kc * 32 + 16);
    const half2* h2a = (const half2*)&hv0;   // h pairs j = 0..3
    const half2* h2b = (const half2*)&hv1;   // h pairs j = 4..7

    float a0 = 0.f, a1 = 0.f, a2 = 0.f, a3 = 0.f;
#pragma unroll
    for (int j = 0; j < 4; ++j) {
      a0 = __builtin_amdgcn_fdot2(h2a[j], u[0][j], a0, false);
      a1 = __builtin_amdgcn_fdot2(h2a[j], u[1][j], a1, false);
      a2 = __builtin_amdgcn_fdot2(h2a[j], u[2][j], a2, false);
      a3 = __builtin_amdgcn_fdot2(h2a[j], u[3][j], a3, false);
    }
#pragma unroll
    for (int j = 0; j < 4; ++j) {
      a0 = __builtin_amdgcn_fdot2(h2b[j], u[0][j + 4], a0, false);
      a1 = __builtin_amdgcn_fdot2(h2b[j], u[1][j + 4], a1, false);
      a2 = __builtin_amdgcn_fdot2(h2b[j], u[2][j + 4], a2, false);
      a3 = __builtin_amdgcn_fdot2(h2b[j], u[3][j + 4], a3, false);
    }

    // Reduce-scatter tree: stage1 xor1 (d2), stage2 xor7 (d1), stage3 xor2.
    const float r0 = a0 + dppx1(a2);
    const float r1 = a1 + dppx1(a3);
    const float t0v = r0 + dppx7(r1);
    const float v = t0v + dppx2(t0v);

    if ((kc & 2) == 0) rec_s[cg * 4 + g] = v + bmine;
    barrier_lds();

    // --- gate phase (first 128 threads; co-resident block overlaps) ---
    if (gateT) {
      const float xz = tof(xzc);
      const float xr = tof(xrc);
      const float xh = tof(xhc);
      const float rz = rec_s[gu];
      const float rr = rec_s[H_ + gu];
      const float rh = rec_s[2 * H_ + gu];
      const float z = fsigmoid(xz + rz);
      const float r = fsigmoid(xr + rr);
      const float hh = ftanh(xh + r * rh);
      const float hn = z * hprev + (1.f - z) * hh;
      hprev = hn;
      hbuf[gu] = (_Float16)hn;
      if constexpr (!LAST) {
        const size_t sidx = ((size_t)b * T_ + t) * (2 * H_) + dir * H_ + gu;
        const unsigned short hi = f2bs(hn);
        seqH[sidx] = hi;
        seqL[sidx] = f2bs(hn - bs2f(hi));
      }
      xzc = xzn;
      xrc = xrn;
      xhc = xhn;
    }
    barrier_lds();
  }

  if constexpr (LAST) {
    if (gateT) fin[(size_t)b * (2 * H_) + dir * H_ + gu] = hprev;
  }
}

// ---------------------------------------------------------------------------
// Dense head: out[b] = sigmoid(fin[b][:] . Wd + bd)
// ---------------------------------------------------------------------------
__global__ void dense_kernel(const float* __restrict__ fin,
                             const float* __restrict__ Wd,
                             const float* __restrict__ bd,
                             float* __restrict__ out) {
  __shared__ float w[2 * H_];
  const int tid = threadIdx.x;
  w[tid] = Wd[tid];
  __syncthreads();
  float s = bd[0];
  const float* row = fin + tid * (2 * H_);
#pragma unroll 8
  for (int jj = 0; jj < 2 * H_; ++jj) s = fmaf(row[jj], w[jj], s);
  out[tid] = 1.f / (1.f + __expf(-s));
}

// ---------------------------------------------------------------------------
template <typename XT>
static void run_model(const float* x, const float* Ws, const float* Us,
                      const float* bs, const float* Wd, const float* bd,
                      float* out, char* ws, hipStream_t stream) {
  const size_t xpB = (size_t)2 * T_ * B_ * G_ * sizeof(XT);
  const size_t seqB = (size_t)B_ * T_ * 2 * H_ * 2;  // bf16 bits
  XT* xp = (XT*)ws;
  ushort* sHA = (ushort*)(ws + xpB);
  ushort* sLA = (ushort*)(ws + xpB + seqB);
  ushort* sHB = (ushort*)(ws + xpB + 2 * seqB);
  ushort* sLB = (ushort*)(ws + xpB + 3 * seqB);
  ushort* WhiT = (ushort*)(ws + xpB + 4 * seqB);
  ushort* WloT = WhiT + (size_t)768 * K_;
  float* fin = (float*)(ws + xpB + 4 * seqB + (size_t)2 * 768 * K_ * 2);

  convX_kernel<<<4096, 256, 0, stream>>>(x, sHB, sLB);

  const ushort* AHs[3] = {sHB, sHA, sHB};
  const ushort* ALs[3] = {sLB, sLA, sLB};
  ushort* oH[3] = {sHA, sHB, nullptr};
  ushort* oL[3] = {sLA, sLB, nullptr};

  for (int l = 0; l < 3; ++l) {
    const float* Wl = Ws + (size_t)l * 2 * K_ * G_;
    const float* bl = bs + (size_t)l * 4 * G_;
    const float* Ul = Us + (size_t)l * 2 * H_ * G_;
    convW_kernel<<<768, 256, 0, stream>>>(Wl, WhiT, WloT);
    gemm3_kernel<XT><<<dim3(M_ / 128, 6), 256, 0, stream>>>(
        AHs[l], ALs[l], WhiT, WloT, bl, xp);
    if (l < 2)
      rec_kernel<XT, false><<<dim3(B_, 2), 768, 0, stream>>>(
          xp, Ul, bl, oH[l], oL[l], nullptr);
    else
      rec_kernel<XT, true><<<dim3(B_, 2), 768, 0, stream>>>(
          xp, Ul, bl, nullptr, nullptr, fin);
  }
  dense_kernel<<<1, B_, 0, stream>>>(fin, Wd, bd, out);
}

extern "C" void kernel_launch(void* const* d_in, const int* in_sizes, int n_in,
                              void* d_out, int out_size, void* d_ws,
                              size_t ws_size, hipStream_t stream) {
  const float* x = (const float*)d_in[0];
  const float* Ws = (const float*)d_in[1];
  const float* Us = (const float*)d_in[2];
  const float* bs = (const float*)d_in[3];
  const float* Wd = (const float*)d_in[4];
  const float* bd = (const float*)d_in[5];
  float* out = (float*)d_out;
  char* ws = (char*)d_ws;

  const size_t seqB = (size_t)B_ * T_ * 2 * H_ * 2;
  const size_t wtB = (size_t)2 * 768 * K_ * 2;
  const size_t finB = (size_t)B_ * 2 * H_ * 4;
  const size_t xp32 = (size_t)2 * T_ * B_ * G_ * 4;
  const size_t tierA = xp32 + 4 * seqB + wtB + finB;      // ~641 MiB, fp32 xp
  if (ws_size >= tierA)
    run_model<float>(x, Ws, Us, bs, Wd, bd, out, ws, stream);
  else
    run_model<bf16>(x, Ws, Us, bs, Wd, bd, out, ws, stream);
}

// Round 15
// 1820.290 us; speedup vs baseline: 2.7004x; 1.1182x over previous
//
#include <hip/hip_runtime.h>
#include <hip/hip_bf16.h>

#define DEV __device__ __forceinline__

constexpr int B_ = 256;   // batch
constexpr int T_ = 512;   // time
constexpr int H_ = 128;   // GRU units
constexpr int K_ = 256;   // input dim per layer (D = 2H = 256 for all layers)
constexpr int G_ = 384;   // 3H
constexpr int M_ = B_ * T_;
constexpr int LDSROW = 72;  // ushorts per LDS tile row (64 data + 8 pad)

using bf16 = __hip_bfloat16;
typedef short short8 __attribute__((ext_vector_type(8)));
typedef _Float16 f16x8 __attribute__((ext_vector_type(8)));
typedef float f32x4 __attribute__((ext_vector_type(4)));
typedef _Float16 half2 __attribute__((ext_vector_type(2)));

DEV float tof(float x) { return x; }
DEV float tof(bf16 x) { return __bfloat162float(x); }
DEV void stor(float* p, float v) { *p = v; }
DEV void stor(bf16* p, float v) { *p = __float2bfloat16(v); }

// float -> f16 bits (RTN via HW convert)
DEV unsigned short f2hs(float f) {
  union { _Float16 h; unsigned short u; } v;
  v.h = (_Float16)f;
  return v.u;
}

// v7: fast-rcp gate math (measured −25us/launch vs IEEE div).
DEV float fsigmoid(float x) {
  return __builtin_amdgcn_rcpf(1.f + __expf(-x));
}
DEV float ftanh(float x) {
  x = fminf(20.f, fmaxf(-20.f, x));
  float e = __expf(-2.f * x);
  return (1.f - e) * __builtin_amdgcn_rcpf(1.f + e);
}

// Barrier draining only LDS traffic (lgkmcnt), not global loads/stores.
DEV void barrier_lds() {
  asm volatile("s_waitcnt lgkmcnt(0)\n\ts_barrier" ::: "memory");
}

// Pin a 32-bit half2 into a VGPR (opaque to the optimizer).
DEV void pinh(half2& v) { asm volatile("" : "+v"(v)); }

DEV f32x4 mfma16h(f16x8 a, f16x8 b, f32x4 c) {
  return __builtin_amdgcn_mfma_f32_16x16x32_f16(a, b, c, 0, 0, 0);
}

// Single-stage DPP exchanges within 8-lane groups (bound_ctrl, full masks).
DEV float dppx1(float x) {  // lane ^ 1 (quad_perm [1,0,3,2])
  return __int_as_float(
      __builtin_amdgcn_update_dpp(0, __float_as_int(x), 0xB1, 0xF, 0xF, true));
}
DEV float dppx2(float x) {  // lane ^ 2 (quad_perm [2,3,0,1])
  return __int_as_float(
      __builtin_amdgcn_update_dpp(0, __float_as_int(x), 0x4E, 0xF, 0xF, true));
}
DEV float dppx7(float x) {  // lane ^ 7 (row_half_mirror)
  return __int_as_float(
      __builtin_amdgcn_update_dpp(0, __float_as_int(x), 0x141, 0xF, 0xF, true));
}

// ---------------------------------------------------------------------------
// convX: fp32 x[M,256] -> f16 single array (v13: no hi/lo split — v12 proved
// f16 on the RECURRENT state leaves absmax bit-identical, so f16 on the
// feed-forward operands has slack too).
// ---------------------------------------------------------------------------
__global__ __launch_bounds__(256) void convX_kernel(
    const float* __restrict__ x, ushort* __restrict__ x16) {
  const int n4 = M_ * K_ / 4;
  for (int idx = blockIdx.x * blockDim.x + threadIdx.x; idx < n4;
       idx += gridDim.x * blockDim.x) {
    float4 v = ((const float4*)x)[idx];
    ushort4 o;
    o.x = f2hs(v.x);
    o.y = f2hs(v.y);
    o.z = f2hs(v.z);
    o.w = f2hs(v.w);
    ((ushort4*)x16)[idx] = o;
  }
}

// ---------------------------------------------------------------------------
// convW: W[dir][256][384] fp32 -> W^T f16 [768 ncol][256 k].
// ---------------------------------------------------------------------------
__global__ __launch_bounds__(256) void convW_kernel(
    const float* __restrict__ W, ushort* __restrict__ WT16) {
  const int ncol = blockIdx.x;           // 0..767
  const int dir = ncol / G_, j = ncol % G_;
  const int k = threadIdx.x;             // 0..255
  WT16[(size_t)ncol * K_ + k] = f2hs(W[((size_t)dir * K_ + k) * G_ + j]);
}

// ---------------------------------------------------------------------------
// gemm1: C[M,768] = A[M,256] @ W^T' + bias, SINGLE-term f16 MFMA.
// v13: drops the 3-term bf16 hi/lo split (3x MFMA work at the m97-structure
// ceiling of ~870 TF -> 178us) for 1-term f16 (~5e-4 rel err on xp; v12
// showed this error class is invisible in absmax). MFMA /3, staging bytes
// /2, LDS 74->37 KB. Fragment layout identical (dtype-independent).
// Waves 0-1 stage A, waves 2-3 stage B.
// ---------------------------------------------------------------------------
template <typename XT>
__global__ __launch_bounds__(256, 2) void gemm1_kernel(
    const ushort* __restrict__ A16, const ushort* __restrict__ BT16,
    const float* __restrict__ bbias, XT* __restrict__ xp) {
  const int m0 = blockIdx.x * 128;
  const int n0 = blockIdx.y * 128;
  const int tid = threadIdx.x;
  const int w = tid >> 6, lane = tid & 63;
  const int wm = w >> 1, wn = w & 1;
  const int col = lane & 15, quad = lane >> 4;

  __shared__ __align__(16) ushort As[128 * LDSROW];
  __shared__ __align__(16) ushort Bs[128 * LDSROW];

  f32x4 acc[4][4];
#pragma unroll
  for (int i = 0; i < 4; ++i)
#pragma unroll
    for (int n = 0; n < 4; ++n) acc[i][n] = (f32x4){0.f, 0.f, 0.f, 0.f};

  const ushort* gsrc = (w < 2) ? A16 : BT16;
  ushort* lds = (w < 2) ? As : Bs;
  const int rbase = (w < 2) ? m0 : n0;
  const int p = (w & 1) * 64 + lane;   // 0..127 within the staging pair

  for (int kb = 0; kb < K_; kb += 64) {
#pragma unroll
    for (int q = 0; q < 8; ++q) {
      const int slot = q * 128 + p;
      const int r = slot >> 3, s = slot & 7;
      short8 v = *(const short8*)(gsrc + (size_t)(rbase + r) * K_ + kb + s * 8);
      *(short8*)&lds[r * LDSROW + s * 8] = v;
    }
    __syncthreads();
#pragma unroll
    for (int z = 0; z < 2; ++z) {
      const int cc8 = (z * 4 + quad) * 8;
      f16x8 a[4], b[4];
#pragma unroll
      for (int i = 0; i < 4; ++i)
        a[i] = *(const f16x8*)&As[(wm * 64 + i * 16 + col) * LDSROW + cc8];
#pragma unroll
      for (int n = 0; n < 4; ++n)
        b[n] = *(const f16x8*)&Bs[(wn * 64 + n * 16 + col) * LDSROW + cc8];
#pragma unroll
      for (int i = 0; i < 4; ++i)
#pragma unroll
        for (int n = 0; n < 4; ++n) acc[i][n] = mfma16h(a[i], b[n], acc[i][n]);
    }
    __syncthreads();
  }

  const int dir = (n0 >= G_) ? 1 : 0;
#pragma unroll
  for (int n = 0; n < 4; ++n) {
    const int ncol = n0 + wn * 64 + n * 16 + col;
    const int g = ncol - dir * G_;
    const float bv = bbias[dir * 2 * G_ + g];
#pragma unroll
    for (int i = 0; i < 4; ++i) {
      const int mb = m0 + wm * 64 + i * 16 + quad * 4;
#pragma unroll
      for (int r = 0; r < 4; ++r) {
        const int m = mb + r;
        const int bb = m >> 9;          // T_ = 512
        const int t = m & (T_ - 1);
        stor(xp + ((size_t)(dir * T_ + t) * B_ + bb) * G_ + g,
             acc[i][n][r] + bv);
      }
    }
  }
}

// ---------------------------------------------------------------------------
// Recurrence, v13 = v12 (measured 465us, VGPR 40, 2 blocks/CU) with the seq
// write reduced to a single f16 value (no hi/lo split — feeds the f16 gemm).
//
// v12 design: U and h as f16 with fdot2 (f16 mul, FP32 accumulate); whole
// kernel fits the <=64-reg occupancy tier (m69: tiers at 64/128/256), so
// grid 512 x 768thr runs 2 blocks/CU and block A's gate/barrier idle is
// covered by block B's dot phase. No waves_per_eu attribute (min-waves
// attributes caused every spill failure: v6/v10/v11).
// Thread = 4 cols x 16 contiguous k; HW-validated reduce-scatter tree:
//   g(kc) = (kc&1?2:0) ^ (kc&4?3:0); stages xor1, xor7, xor2;
//   lanes l and l^2 end duplicated, kc&2==0 writes.
// ---------------------------------------------------------------------------
template <typename XT, bool LAST>
__global__ __attribute__((amdgpu_flat_work_group_size(768, 768))) void
rec_kernel(const XT* __restrict__ xp, const float* __restrict__ Ubase,
           const float* __restrict__ bbase, ushort* __restrict__ seqF,
           float* __restrict__ fin) {
  const int dir = blockIdx.y;
  const int b = blockIdx.x;
  const float* U = Ubase + dir * (H_ * G_);
  const float* bh = bbase + dir * (2 * G_) + G_;
  const int tid = threadIdx.x;
  const int kc = tid & 7;        // position within 8-lane DPP group
  const int cg = tid >> 3;       // column group 0..95

  // Reduce-scatter permutation (v10, HW-validated).
  const int g = ((kc & 1) ? 2 : 0) ^ ((kc & 4) ? 3 : 0);

  __shared__ __align__(16) _Float16 hbuf[H_];   // 256 B
  __shared__ float rec_s[G_];

  // U fragments: u[m][j] = f16 pair {U[k0], U[k0+1]} for col cg*4 + (m^g),
  // k0 = kc*16 + 2j. 32 half2 = 32 VGPRs.
  half2 u[4][8];
#pragma unroll
  for (int m = 0; m < 4; ++m) {
    const int colu = cg * 4 + (m ^ g);
#pragma unroll
    for (int j = 0; j < 8; ++j) {
      const int k0 = kc * 16 + 2 * j;
      u[m][j] = (half2){(_Float16)U[(size_t)k0 * G_ + colu],
                        (_Float16)U[(size_t)(k0 + 1) * G_ + colu]};
      pinh(u[m][j]);
    }
  }

  // This lane's final output after the tree: col cg*4 + g.
  const float bmine = bh[cg * 4 + g];

  const int gu = tid;               // gate-phase unit (tid < 128)
  const bool gateT = tid < H_;

  if (gateT) hbuf[gu] = (_Float16)0.f;

  const XT* xbase = xp + (size_t)(dir * T_) * B_ * G_;

  XT xzc{}, xrc{}, xhc{};
  {
    const int t0 = dir ? (T_ - 1) : 0;
    if (gateT) {
      const XT* xr_ = xbase + ((size_t)t0 * B_ + b) * G_ + gu;
      xzc = xr_[0];
      xrc = xr_[H_];
      xhc = xr_[2 * H_];
    }
  }
  float hprev = 0.f;   // gate thread's own h, carried in-register
  barrier_lds();

  for (int it = 0; it < T_; ++it) {
    const int t = dir ? (T_ - 1 - it) : it;

    // --- prefetch xp for step it+1 (hidden under the dot phase) ---
    XT xzn = xzc, xrn = xrc, xhn = xhc;
    if (gateT && (it + 1 < T_)) {
      const int tn = dir ? (t - 1) : (t + 1);
      const XT* xr_ = xbase + ((size_t)tn * B_ + b) * G_ + gu;
      xzn = xr_[0];
      xrn = xr_[H_];
      xhn = xr_[2 * H_];
    }

    // --- dot phase: 2 broadcast b128 reads of f16 h, 32 fdot2 ---
    float4 hv0 = *(const float4*)((const char*)hbuf + kc * 32);
    float4 hv1 = *(const float4*)((const char*)hbuf + kc * 32 + 16);
    const half2* h2a = (const half2*)&hv0;   // h pairs j = 0..3
    const half2* h2b = (const half2*)&hv1;   // h pairs j = 4..7

    float a0 = 0.f, a1 = 0.f, a2 = 0.f, a3 = 0.f;
#pragma unroll
    for (int j = 0; j < 4; ++j) {
      a0 = __builtin_amdgcn_fdot2(h2a[j], u[0][j], a0, false);
      a1 = __builtin_amdgcn_fdot2(h2a[j], u[1][j], a1, false);
      a2 = __builtin_amdgcn_fdot2(h2a[j], u[2][j], a2, false);
      a3 = __builtin_amdgcn_fdot2(h2a[j], u[3][j], a3, false);
    }
#pragma unroll
    for (int j = 0; j < 4; ++j) {
      a0 = __builtin_amdgcn_fdot2(h2b[j], u[0][j + 4], a0, false);
      a1 = __builtin_amdgcn_fdot2(h2b[j], u[1][j + 4], a1, false);
      a2 = __builtin_amdgcn_fdot2(h2b[j], u[2][j + 4], a2, false);
      a3 = __builtin_amdgcn_fdot2(h2b[j], u[3][j + 4], a3, false);
    }

    // Reduce-scatter tree: stage1 xor1 (d2), stage2 xor7 (d1), stage3 xor2.
    const float r0 = a0 + dppx1(a2);
    const float r1 = a1 + dppx1(a3);
    const float t0v = r0 + dppx7(r1);
    const float v = t0v + dppx2(t0v);

    if ((kc & 2) == 0) rec_s[cg * 4 + g] = v + bmine;
    barrier_lds();

    // --- gate phase (first 128 threads; co-resident block overlaps) ---
    if (gateT) {
      const float xz = tof(xzc);
      const float xr = tof(xrc);
      const float xh = tof(xhc);
      const float rz = rec_s[gu];
      const float rr = rec_s[H_ + gu];
      const float rh = rec_s[2 * H_ + gu];
      const float z = fsigmoid(xz + rz);
      const float r = fsigmoid(xr + rr);
      const float hh = ftanh(xh + r * rh);
      const float hn = z * hprev + (1.f - z) * hh;
      hprev = hn;
      hbuf[gu] = (_Float16)hn;
      if constexpr (!LAST) {
        const size_t sidx = ((size_t)b * T_ + t) * (2 * H_) + dir * H_ + gu;
        seqF[sidx] = f2hs(hn);
      }
      xzc = xzn;
      xrc = xrn;
      xhc = xhn;
    }
    barrier_lds();
  }

  if constexpr (LAST) {
    if (gateT) fin[(size_t)b * (2 * H_) + dir * H_ + gu] = hprev;
  }
}

// ---------------------------------------------------------------------------
// Dense head: out[b] = sigmoid(fin[b][:] . Wd + bd)
// ---------------------------------------------------------------------------
__global__ void dense_kernel(const float* __restrict__ fin,
                             const float* __restrict__ Wd,
                             const float* __restrict__ bd,
                             float* __restrict__ out) {
  __shared__ float w[2 * H_];
  const int tid = threadIdx.x;
  w[tid] = Wd[tid];
  __syncthreads();
  float s = bd[0];
  const float* row = fin + tid * (2 * H_);
#pragma unroll 8
  for (int jj = 0; jj < 2 * H_; ++jj) s = fmaf(row[jj], w[jj], s);
  out[tid] = 1.f / (1.f + __expf(-s));
}

// ---------------------------------------------------------------------------
template <typename XT>
static void run_model(const float* x, const float* Ws, const float* Us,
                      const float* bs, const float* Wd, const float* bd,
                      float* out, char* ws, hipStream_t stream) {
  const size_t xpB = (size_t)2 * T_ * B_ * G_ * sizeof(XT);
  const size_t seqB = (size_t)B_ * T_ * 2 * H_ * 2;  // f16 bytes (= M*K*2)
  XT* xp = (XT*)ws;
  ushort* x16 = (ushort*)(ws + xpB);                 // layer-0 A operand
  ushort* sA = (ushort*)(ws + xpB + seqB);
  ushort* sB = (ushort*)(ws + xpB + 2 * seqB);
  ushort* WT16 = (ushort*)(ws + xpB + 3 * seqB);
  float* fin = (float*)(ws + xpB + 3 * seqB + (size_t)768 * K_ * 2);

  convX_kernel<<<4096, 256, 0, stream>>>(x, x16);

  const ushort* Ain[3] = {x16, sA, sB};
  ushort* seqOut[3] = {sA, sB, nullptr};

  for (int l = 0; l < 3; ++l) {
    const float* Wl = Ws + (size_t)l * 2 * K_ * G_;
    const float* bl = bs + (size_t)l * 4 * G_;
    const float* Ul = Us + (size_t)l * 2 * H_ * G_;
    convW_kernel<<<768, 256, 0, stream>>>(Wl, WT16);
    gemm1_kernel<XT><<<dim3(M_ / 128, 6), 256, 0, stream>>>(
        Ain[l], WT16, bl, xp);
    if (l < 2)
      rec_kernel<XT, false><<<dim3(B_, 2), 768, 0, stream>>>(
          xp, Ul, bl, seqOut[l], nullptr);
    else
      rec_kernel<XT, true><<<dim3(B_, 2), 768, 0, stream>>>(
          xp, Ul, bl, nullptr, fin);
  }
  dense_kernel<<<1, B_, 0, stream>>>(fin, Wd, bd, out);
}

extern "C" void kernel_launch(void* const* d_in, const int* in_sizes, int n_in,
                              void* d_out, int out_size, void* d_ws,
                              size_t ws_size, hipStream_t stream) {
  const float* x = (const float*)d_in[0];
  const float* Ws = (const float*)d_in[1];
  const float* Us = (const float*)d_in[2];
  const float* bs = (const float*)d_in[3];
  const float* Wd = (const float*)d_in[4];
  const float* bd = (const float*)d_in[5];
  float* out = (float*)d_out;
  char* ws = (char*)d_ws;

  const size_t seqB = (size_t)B_ * T_ * 2 * H_ * 2;
  const size_t wtB = (size_t)768 * K_ * 2;
  const size_t finB = (size_t)B_ * 2 * H_ * 4;
  const size_t xp32 = (size_t)2 * T_ * B_ * G_ * 4;
  const size_t tierA = xp32 + 3 * seqB + wtB + finB;      // ~604 MiB, fp32 xp
  if (ws_size >= tierA)
    run_model<float>(x, Ws, Us, bs, Wd, bd, out, ws, stream);
  else
    run_model<bf16>(x, Ws, Us, bs, Wd, bd, out, ws, stream);
}